// Round 10
// baseline (89.979 us; speedup 1.0000x reference)
//
#include <hip/hip_runtime.h>
#include <hip/hip_bf16.h>
#include <math.h>

#define CHN 192
#define BATCHN 65536
#define NS  61                       // transformed-weight slots per channel
#define WSTRIDE 64                   // padded channel stride in ws
#define TROWS 64                     // batch rows per tile/block
#define PAD 193                      // LDS row pitch: (l*193+c)%32 = (l+c)%32 -> 2-way, free
#define BLOCKT 768                   // 12 waves
#define NWAVES (BLOCKT / 64)
#define NITER (CHN / NWAVES)         // 16 channel-iterations per block
#define NTILES (BATCHN / TROWS)      // 1024 blocks

#define KSCALE 2.885390081777926f    // 2*log2(e)
#define LOG2E  1.4426950408889634f

// ---- fast device math -------------------------------------------------------
__device__ __forceinline__ float fast_rcp(float x)  { return __builtin_amdgcn_rcpf(x); }
__device__ __forceinline__ float fast_exp2(float x) { return __builtin_amdgcn_exp2f(x); }
__device__ __forceinline__ float rfl(float v) {
    return __int_as_float(__builtin_amdgcn_readfirstlane(__float_as_int(v)));
}

__device__ __forceinline__ float softplus_acc(float h) {
    if (h > 20.0f) return h;
    return log1pf(expf(h));
}

// ============================================================================
// Kernel A: transform weights ONCE into the scaled domain, CHANNEL-major:
// ws[c*WSTRIDE + s]. Scaled domain: v' = K*v, K=2*log2(e); exp2(t')=e^(2t);
// tanh(t) = 1 - 2*rcp(exp2(t')+1)  (inf-safe: rcp(inf)=0 -> exact saturation).
// slots: 0-2 W0K | 3-5 B0K | 6-8 cp | 9-11 cm | 12-14 gp | 15-17 gm | 18-20 T2_0
//        21-29 W1 | 30-32 B1K | 33-35 T1K1 | 36-38 T2_1
//        39-47 W2 | 48-50 B2K | 51-53 T1K2 | 54-56 T2_2 | 57-59 W3n | 60 b3n
// ============================================================================
__global__ __launch_bounds__(CHN) void weights_kernel(
    const float* __restrict__ a0, const float* __restrict__ a1, const float* __restrict__ a2,
    const float* __restrict__ b0, const float* __restrict__ b1, const float* __restrict__ b2,
    const float* __restrict__ b3,
    const float* __restrict__ H0, const float* __restrict__ H1, const float* __restrict__ H2,
    const float* __restrict__ H3,
    float* __restrict__ ws)
{
    const int c = threadIdx.x;
    float* wc = ws + c * WSTRIDE;
#pragma unroll
    for (int i = 0; i < 3; ++i) {
        float w0k  = KSCALE * softplus_acc(H0[c * 3 + i]);
        float h    = 0.5f * w0k;
        float t1k0 = KSCALE * tanhf(a0[c * 3 + i]);
        wc[0  + i] = w0k;
        wc[3  + i] = KSCALE * b0[c * 3 + i];
        wc[6  + i] = exp2f(h);
        wc[9  + i] = exp2f(-h);
        wc[12 + i] = h + t1k0;
        wc[15 + i] = -h + t1k0;
        wc[18 + i] = -2.0f * t1k0;

        float t1k1 = KSCALE * tanhf(a1[c * 3 + i]);
        wc[30 + i] = KSCALE * b1[c * 3 + i];
        wc[33 + i] = t1k1;
        wc[36 + i] = -2.0f * t1k1;

        float t1k2 = KSCALE * tanhf(a2[c * 3 + i]);
        wc[48 + i] = KSCALE * b2[c * 3 + i];
        wc[51 + i] = t1k2;
        wc[54 + i] = -2.0f * t1k2;

        wc[57 + i] = -0.5f * softplus_acc(H3[c * 3 + i]);
    }
#pragma unroll
    for (int i = 0; i < 9; ++i) {
        wc[21 + i] = softplus_acc(H1[c * 9 + i]);   // (C,3,3) [i][p]
        wc[39 + i] = softplus_acc(H2[c * 9 + i]);
    }
    wc[60] = -LOG2E * b3[c];
}

// ============================================================================
// Kernel B: wave <-> channel; weights live in SGPRs (wave-uniform); x tile
// staged through LDS so both global load and store stay coalesced.
// ============================================================================
__device__ __forceinline__ float density_pair(const float* __restrict__ W, float xv) {
    // ---- L0: one exp2 shared across the +/- CDF branches ----
    float vp[3], vm[3];
#pragma unroll
    for (int i = 0; i < 3; ++i) {
        float q  = fmaf(W[0 + i], xv, W[3 + i]);
        float E  = fast_exp2(q);
        float rp = fast_rcp(fmaf(E, W[6 + i], 1.0f));
        float rm = fast_rcp(fmaf(E, W[9 + i], 1.0f));
        vp[i] = fmaf(W[18 + i], rp, q + W[12 + i]);
        vm[i] = fmaf(W[18 + i], rm, q + W[15 + i]);
    }
    // ---- L1 ----
    float zp[3], zm[3];
#pragma unroll
    for (int p = 0; p < 3; ++p) {
        float tp = W[30 + p], tm = W[30 + p];
#pragma unroll
        for (int i = 0; i < 3; ++i) {
            tp = fmaf(vp[i], W[21 + i * 3 + p], tp);
            tm = fmaf(vm[i], W[21 + i * 3 + p], tm);
        }
        float rp = fast_rcp(fast_exp2(tp) + 1.0f);
        float rm = fast_rcp(fast_exp2(tm) + 1.0f);
        zp[p] = fmaf(W[36 + p], rp, tp + W[33 + p]);
        zm[p] = fmaf(W[36 + p], rm, tm + W[33 + p]);
    }
    // ---- L2 ----
    float yp[3], ym[3];
#pragma unroll
    for (int p = 0; p < 3; ++p) {
        float tp = W[48 + p], tm = W[48 + p];
#pragma unroll
        for (int i = 0; i < 3; ++i) {
            tp = fmaf(zp[i], W[39 + i * 3 + p], tp);
            tm = fmaf(zm[i], W[39 + i * 3 + p], tm);
        }
        float rp = fast_rcp(fast_exp2(tp) + 1.0f);
        float rm = fast_rcp(fast_exp2(tm) + 1.0f);
        yp[p] = fmaf(W[54 + p], rp, tp + W[51 + p]);
        ym[p] = fmaf(W[54 + p], rm, tm + W[51 + p]);
    }
    // ---- L3 + sigmoid (s'' = -log2e*s; p = rcp(exp2(s'')+1)) ----
    float sp = W[60], sm = W[60];
#pragma unroll
    for (int i = 0; i < 3; ++i) {
        sp = fmaf(yp[i], W[57 + i], sp);
        sm = fmaf(ym[i], W[57 + i], sm);
    }
    float pp = fast_rcp(fast_exp2(sp) + 1.0f);
    float pm = fast_rcp(fast_exp2(sm) + 1.0f);
    return pp - pm;
}

__global__ __launch_bounds__(BLOCKT) void density_kernel(
    const float* __restrict__ x,
    const float* __restrict__ wt,
    float* __restrict__ out)
{
    __shared__ float tile[TROWS * PAD];            // 49.4 KB

    const int tid  = threadIdx.x;
    const int g0   = blockIdx.x * (TROWS * CHN);   // flat elem offset of this tile

    // ---- stage in: 12288 floats, coalesced float4 global loads ----
    const float4* x4 = reinterpret_cast<const float4*>(x + g0);
#pragma unroll
    for (int v = 0; v < 4; ++v) {
        int j = v * BLOCKT + tid;                  // float4 index in tile [0,3072)
        float4 d = x4[j];
        int li = 4 * j + j / 48;                   // += row padding (row = j/48)
        tile[li + 0] = d.x; tile[li + 1] = d.y;
        tile[li + 2] = d.z; tile[li + 3] = d.w;
    }
    __syncthreads();

    // ---- compute: wave w handles channel c = k*NWAVES + w; lane = row ----
    const int w = __builtin_amdgcn_readfirstlane(tid >> 6);
    const int l = tid & 63;
    for (int k = 0; k < NITER; ++k) {
        const int c = k * NWAVES + w;              // wave-uniform
        const float* wc = wt + c * WSTRIDE;
        float W[NS];
#pragma unroll
        for (int s = 0; s < NS; ++s) W[s] = rfl(wc[s]);   // SGPR-resident weights

        const int li = l * PAD + c;                // bank = (l+c)%32 -> 2-way, free
        float xv = tile[li];
        tile[li] = density_pair(W, xv);            // elementwise: write back in place
    }
    __syncthreads();

    // ---- stage out: coalesced float4 global stores ----
    float4* o4 = reinterpret_cast<float4*>(out + g0);
#pragma unroll
    for (int v = 0; v < 4; ++v) {
        int j = v * BLOCKT + tid;
        int li = 4 * j + j / 48;
        float4 d;
        d.x = tile[li + 0]; d.y = tile[li + 1];
        d.z = tile[li + 2]; d.w = tile[li + 3];
        o4[j] = d;
    }
}

extern "C" void kernel_launch(void* const* d_in, const int* in_sizes, int n_in,
                              void* d_out, int out_size, void* d_ws, size_t ws_size,
                              hipStream_t stream) {
    const float* x  = (const float*)d_in[0];
    const float* a0 = (const float*)d_in[1];
    const float* a1 = (const float*)d_in[2];
    const float* a2 = (const float*)d_in[3];
    const float* b0 = (const float*)d_in[4];
    const float* b1 = (const float*)d_in[5];
    const float* b2 = (const float*)d_in[6];
    const float* b3 = (const float*)d_in[7];
    const float* H0 = (const float*)d_in[8];
    const float* H1 = (const float*)d_in[9];
    const float* H2 = (const float*)d_in[10];
    const float* H3 = (const float*)d_in[11];
    float* out = (float*)d_out;
    float* ws  = (float*)d_ws;   // needs CHN*WSTRIDE*4 = 48 KB

    weights_kernel<<<1, CHN, 0, stream>>>(a0, a1, a2, b0, b1, b2, b3,
                                          H0, H1, H2, H3, ws);
    density_kernel<<<NTILES, BLOCKT, 0, stream>>>(x, ws, out);
}

// Round 11
// 82.091 us; speedup vs baseline: 1.0961x; 1.0961x over previous
//
#include <hip/hip_runtime.h>
#include <hip/hip_bf16.h>
#include <math.h>

#define CHN 192
#define BATCHN 65536
#define NBLOCKS 4096
#define ROWS_PER_BLOCK (BATCHN / NBLOCKS)   // 16
#define NWS 61                               // transformed-weight slots per channel

#define KSCALE 2.885390081777926f   // 2*log2(e)
#define LOG2E  1.4426950408889634f

// ---- fast device math -------------------------------------------------------
__device__ __forceinline__ float fast_rcp(float x)  { return __builtin_amdgcn_rcpf(x); }
__device__ __forceinline__ float fast_exp2(float x) { return __builtin_amdgcn_exp2f(x); }
__device__ __forceinline__ void pinf(float& v) { asm volatile("" : "+v"(v)); }

__device__ __forceinline__ float softplus_acc(float h) {
    if (h > 20.0f) return h;
    return log1pf(expf(h));
}

// ============================================================================
// Kernel A: transform weights ONCE into the scaled domain, slot-major in ws.
// Scaled domain: v' = K*v, K = 2*log2(e); exp2(t') = e^(2t);
// tanh(t) = 1 - 2*rcp(exp2(t')+1)  (sign-correct for all t; inf-safe: rcp(inf)=0).
// slot map (ws[s*CHN + c]):
//   0-2  W0K   3-5  B0K   6-8  cp    9-11 cm   12-14 gp  15-17 gm  18-20 T2_0
//   21-29 W1  30-32 B1K  33-35 T1K1 36-38 T2_1
//   39-47 W2  48-50 B2K  51-53 T1K2 54-56 T2_2
//   57-59 W3n 60 b3n
// ============================================================================
__global__ __launch_bounds__(CHN) void weights_kernel(
    const float* __restrict__ a0, const float* __restrict__ a1, const float* __restrict__ a2,
    const float* __restrict__ b0, const float* __restrict__ b1, const float* __restrict__ b2,
    const float* __restrict__ b3,
    const float* __restrict__ H0, const float* __restrict__ H1, const float* __restrict__ H2,
    const float* __restrict__ H3,
    float* __restrict__ ws)
{
    const int c = threadIdx.x;
#pragma unroll
    for (int i = 0; i < 3; ++i) {
        float w0k = KSCALE * softplus_acc(H0[c * 3 + i]);
        float h   = 0.5f * w0k;
        float t1k0 = KSCALE * tanhf(a0[c * 3 + i]);
        ws[(0  + i) * CHN + c] = w0k;
        ws[(3  + i) * CHN + c] = KSCALE * b0[c * 3 + i];
        ws[(6  + i) * CHN + c] = exp2f(h);
        ws[(9  + i) * CHN + c] = exp2f(-h);
        ws[(12 + i) * CHN + c] = h + t1k0;
        ws[(15 + i) * CHN + c] = -h + t1k0;
        ws[(18 + i) * CHN + c] = -2.0f * t1k0;

        float t1k1 = KSCALE * tanhf(a1[c * 3 + i]);
        ws[(30 + i) * CHN + c] = KSCALE * b1[c * 3 + i];
        ws[(33 + i) * CHN + c] = t1k1;
        ws[(36 + i) * CHN + c] = -2.0f * t1k1;

        float t1k2 = KSCALE * tanhf(a2[c * 3 + i]);
        ws[(48 + i) * CHN + c] = KSCALE * b2[c * 3 + i];
        ws[(51 + i) * CHN + c] = t1k2;
        ws[(54 + i) * CHN + c] = -2.0f * t1k2;

        ws[(57 + i) * CHN + c] = -0.5f * softplus_acc(H3[c * 3 + i]);
    }
#pragma unroll
    for (int i = 0; i < 9; ++i) {
        ws[(21 + i) * CHN + c] = softplus_acc(H1[c * 9 + i]);   // (C,3,3) [i][p]
        ws[(39 + i) * CHN + c] = softplus_acc(H2[c * 9 + i]);
    }
    ws[60 * CHN + c] = -LOG2E * b3[c];
}

// ============================================================================
// Kernel B: zero libm; scalar exp2/rcp on the quarter-rate trans pipe.
// R11 change vs R9: __launch_bounds__(CHN, 1) — R9's missing min-waves arg
// made the allocator cap at VGPR=44 and spill the 61 pinned weights to
// scratch (pins forbid remat, so spill was the only fallback).
// ============================================================================
__device__ __forceinline__ float density_pair(const float* __restrict__ W, float xv) {
    // ---- L0: one exp2 shared across the +/- CDF branches ----
    float vp[3], vm[3];
#pragma unroll
    for (int i = 0; i < 3; ++i) {
        float q  = fmaf(W[0 + i], xv, W[3 + i]);
        float E  = fast_exp2(q);
        float rp = fast_rcp(fmaf(E, W[6 + i], 1.0f));
        float rm = fast_rcp(fmaf(E, W[9 + i], 1.0f));
        vp[i] = fmaf(W[18 + i], rp, q + W[12 + i]);
        vm[i] = fmaf(W[18 + i], rm, q + W[15 + i]);
    }
    // ---- L1 ----
    float zp[3], zm[3];
#pragma unroll
    for (int p = 0; p < 3; ++p) {
        float tp = W[30 + p], tm = W[30 + p];
#pragma unroll
        for (int i = 0; i < 3; ++i) {
            tp = fmaf(vp[i], W[21 + i * 3 + p], tp);
            tm = fmaf(vm[i], W[21 + i * 3 + p], tm);
        }
        float rp = fast_rcp(fast_exp2(tp) + 1.0f);
        float rm = fast_rcp(fast_exp2(tm) + 1.0f);
        zp[p] = fmaf(W[36 + p], rp, tp + W[33 + p]);
        zm[p] = fmaf(W[36 + p], rm, tm + W[33 + p]);
    }
    // ---- L2 ----
    float yp[3], ym[3];
#pragma unroll
    for (int p = 0; p < 3; ++p) {
        float tp = W[48 + p], tm = W[48 + p];
#pragma unroll
        for (int i = 0; i < 3; ++i) {
            tp = fmaf(zp[i], W[39 + i * 3 + p], tp);
            tm = fmaf(zm[i], W[39 + i * 3 + p], tm);
        }
        float rp = fast_rcp(fast_exp2(tp) + 1.0f);
        float rm = fast_rcp(fast_exp2(tm) + 1.0f);
        yp[p] = fmaf(W[54 + p], rp, tp + W[51 + p]);
        ym[p] = fmaf(W[54 + p], rm, tm + W[51 + p]);
    }
    // ---- L3 + sigmoid (s'' = -log2e*s; p = rcp(exp2(s'')+1)) ----
    float sp = W[60], sm = W[60];
#pragma unroll
    for (int i = 0; i < 3; ++i) {
        sp = fmaf(yp[i], W[57 + i], sp);
        sm = fmaf(ym[i], W[57 + i], sm);
    }
    float pp = fast_rcp(fast_exp2(sp) + 1.0f);
    float pm = fast_rcp(fast_exp2(sm) + 1.0f);
    return pp - pm;
}

__global__ __launch_bounds__(CHN, 1) void density_kernel(
    const float* __restrict__ x,
    const float* __restrict__ wt,
    float* __restrict__ out)
{
    const int c = threadIdx.x;          // thread <-> channel

    float W[NWS];
#pragma unroll
    for (int s = 0; s < NWS; ++s) W[s] = wt[s * CHN + c];   // 61 coalesced dwords
#pragma unroll
    for (int s = 0; s < NWS; ++s) pinf(W[s]);               // keep register-resident

    const int b_start = blockIdx.x * ROWS_PER_BLOCK;
#pragma unroll 2
    for (int r = 0; r < ROWS_PER_BLOCK; ++r) {
        const int idx = (b_start + r) * CHN + c;
        out[idx] = density_pair(W, x[idx]);
    }
}

extern "C" void kernel_launch(void* const* d_in, const int* in_sizes, int n_in,
                              void* d_out, int out_size, void* d_ws, size_t ws_size,
                              hipStream_t stream) {
    const float* x  = (const float*)d_in[0];
    const float* a0 = (const float*)d_in[1];
    const float* a1 = (const float*)d_in[2];
    const float* a2 = (const float*)d_in[3];
    const float* b0 = (const float*)d_in[4];
    const float* b1 = (const float*)d_in[5];
    const float* b2 = (const float*)d_in[6];
    const float* b3 = (const float*)d_in[7];
    const float* H0 = (const float*)d_in[8];
    const float* H1 = (const float*)d_in[9];
    const float* H2 = (const float*)d_in[10];
    const float* H3 = (const float*)d_in[11];
    float* out = (float*)d_out;
    float* ws  = (float*)d_ws;   // needs NWS*CHN*4 = 46.9 KB

    weights_kernel<<<1, CHN, 0, stream>>>(a0, a1, a2, b0, b1, b2, b3,
                                          H0, H1, H2, H3, ws);
    density_kernel<<<NBLOCKS, CHN, 0, stream>>>(x, ws, out);
}